// Round 7
// baseline (366.569 us; speedup 1.0000x reference)
//
#include <hip/hip_runtime.h>
#include <hip/hip_bf16.h>

using bf16 = __hip_bfloat16;

typedef __attribute__((ext_vector_type(8))) short bf16x8;
typedef __attribute__((ext_vector_type(4))) float f32x4;

// async global->LDS, 16 B per lane, wave-uniform LDS base (+lane*16 by HW).
__device__ __forceinline__ void async16(const void* g, void* l) {
  __builtin_amdgcn_global_load_lds(
      (const __attribute__((address_space(1))) unsigned int*)g,
      (__attribute__((address_space(3))) unsigned int*)l, 16, 0, 0);
}

__device__ __forceinline__ void store_o(float* C, size_t i, float v) { C[i] = v; }
__device__ __forceinline__ void store_o(bf16* C, size_t i, float v) {
  C[i] = __float2bfloat16(v);
}

// ---------------------------------------------------------------------------
// K1: backbone conv (3->256, 3x3, stride16, pad1) fused with 2x2 avgpool.
// Output f NHWC fp32 (8,32,32,256). One block per (b,y,x), thread=cout.
// ---------------------------------------------------------------------------
__global__ __launch_bounds__(256) void k_backbone(const float* __restrict__ img,
    const float* __restrict__ w, const float* __restrict__ bias,
    float* __restrict__ f) {
  int blk = blockIdx.x;
  int x = blk & 31, y = (blk >> 5) & 31, b = blk >> 10;
  __shared__ float patch[4 * 27];   // [sub][cin*9+ky*3+kx]
  int t = threadIdx.x;
  if (t < 108) {
    int kx = t % 3, ky = (t / 3) % 3, cin = (t / 9) % 3, sub = t / 27;
    int sy = sub >> 1, sx = sub & 1;
    int iy = (2 * y + sy) * 16 - 1 + ky;   // max 1009 < 1024
    int ix = (2 * x + sx) * 16 - 1 + kx;
    float v = 0.f;
    if (iy >= 0 && ix >= 0)
      v = img[((size_t)(b * 3 + cin) * 1024 + iy) * 1024 + ix];
    patch[t] = v;
  }
  __syncthreads();
  int c = t;
  float wr[27];
#pragma unroll
  for (int k = 0; k < 27; ++k) wr[k] = w[c * 27 + k];
  float acc = 0.f;
#pragma unroll
  for (int sub = 0; sub < 4; ++sub)
#pragma unroll
    for (int k = 0; k < 27; ++k)
      acc += patch[sub * 27 + k] * wr[k];
  f[(size_t)blk * 256 + c] = acc * 0.25f + bias[c];
}

// ---------------------------------------------------------------------------
// K2a: RPN conv partials. grid (pos=32, kc=16), thread = cout.
// ---------------------------------------------------------------------------
__global__ __launch_bounds__(256) void k_rpn(const float* __restrict__ f,
    const float* __restrict__ rpn_w, float* __restrict__ part) {
  int p = blockIdx.x;        // 0..31 : b*4 + x
  int kc = blockIdx.y;       // 0..15 : 16-cin chunk
  int x = p & 3, b = p >> 2;
  __shared__ float fpl[6][16];   // [row*3+col][cin2]
  int tid = threadIdx.x;
  if (tid < 96) {
    int cin2 = tid & 15;
    int rc = tid >> 4;       // 0..5 = row*3+col
    int row = rc / 3, col = rc % 3;
    int xc = x - 1 + col;    // <= 5, always < 32
    float v = 0.f;
    if (xc >= 0)
      v = f[((size_t)(b * 32 + row) * 32 + xc) * 256 + kc * 16 + cin2];
    fpl[rc][cin2] = v;
  }
  __syncthreads();
  int c = tid;
  const float* wbase = rpn_w + (size_t)c * 2304 + kc * 144;
  float acc = 0.f;
#pragma unroll
  for (int cin2 = 0; cin2 < 16; ++cin2) {
    const float* wp = wbase + cin2 * 9;
    acc += fpl[0][cin2] * wp[3] + fpl[1][cin2] * wp[4]
         + fpl[2][cin2] * wp[5] + fpl[3][cin2] * wp[6]
         + fpl[4][cin2] * wp[7] + fpl[5][cin2] * wp[8];
  }
  part[((size_t)kc * 32 + p) * 256 + c] = acc;
}

// ---------------------------------------------------------------------------
// K2b: reduce partials + ReLU, delta conv (2 threads per output), decode.
// ---------------------------------------------------------------------------
__global__ __launch_bounds__(512) void k_delta(const float* __restrict__ part,
    const float* __restrict__ rpn_b,
    const float* __restrict__ dw, const float* __restrict__ db,
    float* __restrict__ boxes) {
  int p = blockIdx.x;        // 0..31
  int x = p & 3, b = p >> 2;
  __shared__ float tbuf[256];
  __shared__ float dvals[135];
  int tid = threadIdx.x;
  if (tid < 256) {
    float s = rpn_b[tid];
#pragma unroll
    for (int kc = 0; kc < 16; ++kc)
      s += part[((size_t)kc * 32 + p) * 256 + tid];
    tbuf[tid] = fmaxf(s, 0.f);
  }
  __syncthreads();
  if (tid < 270) {
    int o = tid >> 1, half = tid & 1;
    const float* wp = dw + (size_t)o * 256 + half * 128;
    const float* tp = tbuf + half * 128;
    float s = 0.f;
#pragma unroll 8
    for (int k = 0; k < 128; ++k) s += tp[k] * wp[k];
    s += __shfl_xor(s, 1, 64);   // pair (2o, 2o+1) always within one wave
    if (half == 0) dvals[o] = s + db[o];
  }
  __syncthreads();
  if (tid < 27) {
    int i = x * 27 + tid;
    if (i < 100) {
      int a = tid;
      int si = a / 9, ri = (a / 3) % 3, ai = a % 3;
      float scale = 32.f * (float)(1 << si);
      float sr = (ri == 0) ? 0.70710678118654752f : (ri == 1 ? 1.0f : 1.41421356237309505f);
      float aw = scale * sr, ah = scale / sr;
      float aang = 45.f * (float)ai;
      float acx = 32.f * (float)x, acy = 0.f;
      float* bx = boxes + (size_t)(b * 100 + i) * 5;
      bx[0] = dvals[a * 5 + 0] * aw + acx;
      bx[1] = dvals[a * 5 + 1] * ah + acy;
      bx[2] = expf(dvals[a * 5 + 2]) * aw;
      bx[3] = expf(dvals[a * 5 + 3]) * ah;
      bx[4] = aang + dvals[a * 5 + 4];
    }
  }
}

// ---------------------------------------------------------------------------
// K3: rotated ROI align. 800 blocks, thread=channel; writes pooled as bf16
// in (n, c*49+bin) order — the A operand of the FC1 MFMA GEMM.
// ---------------------------------------------------------------------------
__global__ __launch_bounds__(256) void k_roialign(const float* __restrict__ f,
    const float* __restrict__ boxes, bf16* __restrict__ pooled) {
  int n = blockIdx.x;
  int b = n / 100;
  __shared__ int six[49], siy[49];
  __shared__ float swx[49], swy[49];
  __shared__ float pool_s[12544];
  int tid = threadIdx.x;
  if (tid < 49) {
    float cx = boxes[n * 5 + 0], cy = boxes[n * 5 + 1];
    float w = boxes[n * 5 + 2], h = boxes[n * 5 + 3], ang = boxes[n * 5 + 4];
    float ar = -ang * 0.017453292519943295f;
    float cc = cosf(ar), ss = sinf(ar);
    float t00 = w * (1.f / 32.f) * cc, t01 = -h * (1.f / 32.f) * ss;
    float t02 = cx * (2.f / 32.f) - 1.f;
    float t10 = w * (1.f / 32.f) * ss, t11 = h * (1.f / 32.f) * cc;
    float t12 = cy * (2.f / 32.f) - 1.f;
    int py = tid / 7, px = tid - py * 7;
    float lx = (2.f * px + 1.f) * (1.f / 7.f) - 1.f;
    float ly = (2.f * py + 1.f) * (1.f / 7.f) - 1.f;
    float gx = t00 * lx + t01 * ly + t02;
    float gy = t10 * lx + t11 * ly + t12;
    float ix = ((gx + 1.f) * 32.f - 1.f) * 0.5f;
    float iy = ((gy + 1.f) * 32.f - 1.f) * 0.5f;
    float x0 = floorf(ix), y0 = floorf(iy);
    six[tid] = (int)x0; siy[tid] = (int)y0;
    swx[tid] = ix - x0; swy[tid] = iy - y0;
  }
  __syncthreads();
  const float* fb = f + (size_t)b * 262144;
  int c = tid;
  for (int bin = 0; bin < 49; ++bin) {
    int x0 = six[bin], y0 = siy[bin];
    float wx = swx[bin], wy = swy[bin];
    float acc = 0.f;
    if (x0 >= 0 && x0 < 32 && y0 >= 0 && y0 < 32)
      acc += fb[(y0 * 32 + x0) * 256 + c] * ((1.f - wx) * (1.f - wy));
    if (x0 + 1 >= 0 && x0 + 1 < 32 && y0 >= 0 && y0 < 32)
      acc += fb[(y0 * 32 + x0 + 1) * 256 + c] * (wx * (1.f - wy));
    if (x0 >= 0 && x0 < 32 && y0 + 1 >= 0 && y0 + 1 < 32)
      acc += fb[((y0 + 1) * 32 + x0) * 256 + c] * ((1.f - wx) * wy);
    if (x0 + 1 >= 0 && x0 + 1 < 32 && y0 + 1 >= 0 && y0 + 1 < 32)
      acc += fb[((y0 + 1) * 32 + x0 + 1) * 256 + c] * (wx * wy);
    pool_s[c * 49 + bin] = acc;
  }
  __syncthreads();
  bf16* po = pooled + (size_t)n * 12544;
  for (int k = tid; k < 12544; k += 256) po[k] = __float2bfloat16(pool_s[k]);
}

// ---------------------------------------------------------------------------
// K-cvtz: merged: fc1_w fp32->bf16, fc2_w fp32->bf16, zero P. One launch.
// ---------------------------------------------------------------------------
__device__ __forceinline__ unsigned int pk2(float a, float b) {
  unsigned int ua = __bfloat16_as_ushort(__float2bfloat16(a));
  unsigned int ub = __bfloat16_as_ushort(__float2bfloat16(b));
  return ua | (ub << 16);
}
__global__ __launch_bounds__(256) void k_cvtz(const float* __restrict__ s1,
    const float* __restrict__ s2, uint2* __restrict__ d1,
    uint2* __restrict__ d2, f32x4* __restrict__ Pz) {
  const int N1 = 3211264;   // fc1_w float4s (1024*12544/4)
  const int N2 = 262144;    // fc2_w float4s (1024*1024/4)
  const int NZ = 204800;    // P float4s (800*1024/4)
  int stride = gridDim.x * 256;
  for (int j = blockIdx.x * 256 + threadIdx.x; j < N1 + N2 + NZ; j += stride) {
    if (j < N1) {
      float4 v = ((const float4*)s1)[j];
      uint2 o; o.x = pk2(v.x, v.y); o.y = pk2(v.z, v.w);
      d1[j] = o;
    } else if (j < N1 + N2) {
      int i = j - N1;
      float4 v = ((const float4*)s2)[i];
      uint2 o; o.x = pk2(v.x, v.y); o.y = pk2(v.z, v.w);
      d2[i] = o;
    } else {
      Pz[j - N1 - N2] = (f32x4){0.f, 0.f, 0.f, 0.f};
    }
  }
}

// ---------------------------------------------------------------------------
// K4: both-bf16 split-K MFMA GEMM, counted-vmcnt double-buffer (T3+T4) +
// XCD-PINNED split-K (T1): all 56 tile-blocks of K-chunk z land on XCD z%8
// (dispatcher round-robins XCD = blockIdx % 8). Per-z working set (A-chunk
// 128..800 rows x KC x bf16 + B-chunk) ~3.3 MB -> fits one XCD's 4 MB L2:
// chunk fetched from HBM once, re-reads are ~200cy L2 hits which the 1-step
// counted-vmcnt prefetch fully hides.
// Block decode: b = (z%8) + 8*(56*(z/8) + t); t = bx + 8*by (bx: n-tile 0..7,
// by: m-tile 0..6). Blocks with z*KC >= K exit immediately (idle padding).
// Tile 128x128, BK=64, 4 waves (2x2), 32 MFMA/wave/step, atomic accum.
// ---------------------------------------------------------------------------
__global__ __launch_bounds__(256) void k_gemm_bb(
    const unsigned short* __restrict__ A, const unsigned short* __restrict__ B,
    float* __restrict__ P, int M, int N, int K, int KC) {
  int b = blockIdx.x;
  int x8 = b & 7, j = b >> 3;
  int g = j / 56, t2 = j - g * 56;
  int z = x8 + 8 * g;
  int kbeg = z * KC;
  if (kbeg >= K) return;                   // idle padding block
  int kend = kbeg + KC; if (kend > K) kend = K;
  int n0 = (t2 & 7) * 128;                 // n-tile (N=1024 -> 8 tiles)
  int m0 = (t2 >> 3) * 128;                // m-tile (M=800  -> 7 tiles)

  __shared__ unsigned short As[2][128 * 64];  // 2 x 16 KB
  __shared__ unsigned short Bs[2][128 * 64];  // 2 x 16 KB
  int t = threadIdx.x;
  int wv = t >> 6, ln = t & 63;
  int quad = ln >> 4, l15 = ln & 15;
  int wm = wv >> 1, wn = wv & 1;           // 2x2 wave grid

  // Staging: lane (srow, sg): within-8-row-group row srow, global seg
  // sg = (ln&7)^srow lands at linear LDS slot (ln&7) -> XOR swizzle.
  int srow = ln >> 3;                      // 0..7
  int sg = (ln & 7) ^ srow;
  const unsigned short* Ap[4];
#pragma unroll
  for (int q = 0; q < 4; ++q) {
    int r = m0 + q * 32 + wv * 8 + srow;   // within-tile row & 7 == srow
    if (r > M - 1) r = M - 1;
    Ap[q] = A + (size_t)r * K + sg * 8;
  }
  const unsigned short* Bp[4];
#pragma unroll
  for (int c = 0; c < 4; ++c) {
    int r = n0 + wv * 32 + c * 8 + srow;   // N=1024: always in range
    Bp[c] = B + (size_t)r * K + sg * 8;
  }

  f32x4 acc[4][4];
#pragma unroll
  for (int mf = 0; mf < 4; ++mf)
#pragma unroll
    for (int nf = 0; nf < 4; ++nf) acc[mf][nf] = (f32x4){0.f, 0.f, 0.f, 0.f};

  // prologue: stage tile kbeg into buffer 0 (8 async16/wave, in flight)
#pragma unroll
  for (int q = 0; q < 4; ++q)
    async16(Ap[q] + kbeg, &As[0][q * 2048 + wv * 512]);
#pragma unroll
  for (int c = 0; c < 4; ++c)
    async16(Bp[c] + kbeg, &Bs[0][wv * 2048 + c * 512]);

  int cur = 0;
  for (int k0 = kbeg; k0 < kend; k0 += 64) {
    int k1 = k0 + 64;
    if (k1 < kend) {
      // stage next tile into buf^1 (that buffer's readers finished at the
      // barrier that ended the previous iteration -> WAR-safe).
#pragma unroll
      for (int q = 0; q < 4; ++q)
        async16(Ap[q] + k1, &As[cur ^ 1][q * 2048 + wv * 512]);
#pragma unroll
      for (int c = 0; c < 4; ++c)
        async16(Bp[c] + k1, &Bs[cur ^ 1][wv * 2048 + c * 512]);
      // wait for the OLD 8 only; the new 8 stay in flight across the barrier
      asm volatile("s_waitcnt vmcnt(8)" ::: "memory");
    } else {
      asm volatile("s_waitcnt vmcnt(0)" ::: "memory");
    }
    __builtin_amdgcn_s_barrier();          // all waves: buf[cur] resident
    __builtin_amdgcn_sched_barrier(0);
#pragma unroll
    for (int ks = 0; ks < 2; ++ks) {
      bf16x8 a[4];
#pragma unroll
      for (int mf = 0; mf < 4; ++mf) {
        int row = wm * 64 + mf * 16 + l15;           // row & 7 == l15 & 7
        a[mf] = *(const bf16x8*)&As[cur][row * 64 + (((ks * 4 + quad) ^ (l15 & 7)) * 8)];
      }
#pragma unroll
      for (int nf = 0; nf < 4; ++nf) {
        int brow = wn * 64 + nf * 16 + l15;
        bf16x8 b2 = *(const bf16x8*)&Bs[cur][brow * 64 + (((ks * 4 + quad) ^ (l15 & 7)) * 8)];
#pragma unroll
        for (int mf = 0; mf < 4; ++mf)
          acc[mf][nf] = __builtin_amdgcn_mfma_f32_16x16x32_bf16(a[mf], b2, acc[mf][nf], 0, 0, 0);
      }
    }
    __builtin_amdgcn_sched_barrier(0);
    asm volatile("" ::: "memory");
    __builtin_amdgcn_s_barrier();          // readers of buf[cur] done ->
    cur ^= 1;                              // next iter may restage into it
  }
  // atomic accumulate; D layout m = quad*4+r, n = l15 (within 16x16).
#pragma unroll
  for (int nf = 0; nf < 4; ++nf) {
    int n = n0 + wn * 64 + nf * 16 + l15;
#pragma unroll
    for (int mf = 0; mf < 4; ++mf) {
#pragma unroll
      for (int r = 0; r < 4; ++r) {
        int m = m0 + wm * 64 + mf * 16 + quad * 4 + r;
        if (m < M) atomicAdd(&P[(size_t)m * N + n], acc[mf][nf][r]);
      }
    }
  }
}

// ---------------------------------------------------------------------------
// K5: bias + ReLU epilogue: C = relu(P + bias). Optionally re-zeros P for
// the next atomic GEMM (saves a memset launch). float4-vectorized.
// ---------------------------------------------------------------------------
template <typename OutT, bool RZ>
__global__ __launch_bounds__(256) void k_bias_relu(float* __restrict__ P,
    const float* __restrict__ bias, OutT* __restrict__ C, int MN, int N) {
  int i = blockIdx.x * 256 + threadIdx.x;   // float4 index
  if (i * 4 >= MN) return;
  f32x4 s = *(const f32x4*)(P + (size_t)i * 4);
  int n = (i * 4) % N;
#pragma unroll
  for (int u = 0; u < 4; ++u)
    store_o(C, (size_t)i * 4 + u, fmaxf(s[u] + bias[n + u], 0.f));
  if (RZ) *(f32x4*)(P + (size_t)i * 4) = (f32x4){0.f, 0.f, 0.f, 0.f};
}

// ---------------------------------------------------------------------------
// K6: heads. One block per row, one wave per output (5 cls + 5 bbox).
// ---------------------------------------------------------------------------
__global__ __launch_bounds__(640) void k_heads(const float* __restrict__ x2,
    const float* __restrict__ cls_w, const float* __restrict__ cls_b,
    const float* __restrict__ bbox_w, const float* __restrict__ bbox_b,
    float* __restrict__ out) {
  int n = blockIdx.x;
  int wave = threadIdx.x >> 6;   // 0..9
  int lane = threadIdx.x & 63;
  const float* w = (wave < 5) ? (cls_w + (size_t)wave * 1024)
                              : (bbox_w + (size_t)(wave - 5) * 1024);
  const float* xr = x2 + (size_t)n * 1024;
  float s = 0.f;
  for (int k = lane; k < 1024; k += 64) s += xr[k] * w[k];
  for (int off = 32; off; off >>= 1) s += __shfl_down(s, off, 64);
  if (lane == 0) {
    int o = (wave < 5) ? wave : wave - 5;
    float bias = (wave < 5) ? cls_b[o] : bbox_b[o];
    int base = (wave < 5) ? 0 : 4000;
    out[base + n * 5 + o] = s + bias;
  }
}

// ---------------------------------------------------------------------------
extern "C" void kernel_launch(void* const* d_in, const int* in_sizes, int n_in,
                              void* d_out, int out_size, void* d_ws, size_t ws_size,
                              hipStream_t stream) {
  const float* images     = (const float*)d_in[0];
  const float* backbone_w = (const float*)d_in[1];
  const float* backbone_b = (const float*)d_in[2];
  const float* rpn_w      = (const float*)d_in[3];
  const float* rpn_b      = (const float*)d_in[4];
  // d_in[5]/d_in[6] (obj_w/obj_b): conv output unused by the reference.
  const float* delta_w    = (const float*)d_in[7];
  const float* delta_b    = (const float*)d_in[8];
  const float* fc1_w      = (const float*)d_in[9];
  const float* fc1_b      = (const float*)d_in[10];
  const float* fc2_w      = (const float*)d_in[11];
  const float* fc2_b      = (const float*)d_in[12];
  const float* cls_w      = (const float*)d_in[13];
  const float* cls_b      = (const float*)d_in[14];
  const float* bbox_w     = (const float*)d_in[15];
  const float* bbox_b     = (const float*)d_in[16];

  // Workspace layout (52.79 MB total; aliases are stream-ordered):
  //   bw1 @ 0          : 25,690,112 B (fc1_w bf16)  -- ALIASES f (8.39 MB,
  //                      dead after k_roialign; k_cvtz runs after it)
  //   boxes @25,690,112:     16,384 B
  //   pooled@25,706,496: 20,070,400 B -- ALIASES x2 (3.28 MB, written by FC2
  //                      bias_relu when pooled is dead)
  //   x1   @45,776,896 :  1,638,400 B
  //   P    @47,415,296 :  3,276,800 B (atomic accum; also rpn partials)
  //   bw2  @50,692,096 :  2,097,152 B (fc2_w bf16)
  char* ws = (char*)d_ws;
  bf16*  bw1    = (bf16*) ws;
  float* f      = (float*)ws;                  // phase-1 only
  float* boxes  = (float*)(ws + 25690112);
  bf16*  pooled = (bf16*) (ws + 25706496);
  float* x2     = (float*)(ws + 25706496);     // alias, phase-3
  bf16*  x1     = (bf16*) (ws + 45776896);
  float* P      = (float*)(ws + 47415296);
  bf16*  bw2    = (bf16*) (ws + 50692096);
  float* rpart  = P;

  k_backbone<<<8192, 256, 0, stream>>>(images, backbone_w, backbone_b, f);
  k_rpn<<<dim3(32, 16), 256, 0, stream>>>(f, rpn_w, rpart);
  k_delta<<<32, 512, 0, stream>>>(rpart, rpn_b, delta_w, delta_b, boxes);
  k_roialign<<<800, 256, 0, stream>>>(f, boxes, pooled);

  // merged: weight pre-conversion (f dead; bw1 overwrites) + zero P
  k_cvtz<<<2048, 256, 0, stream>>>(fc1_w, fc2_w, (uint2*)bw1, (uint2*)bw2,
                                   (f32x4*)P);

  // FC1: K=12544, KS=14 (KC=896, 14 steps). XCD-pinned grid: 896 blocks
  // (784 working + 112 idle pads so that XCD(b)=b%8 == z%8).
  k_gemm_bb<<<896, 256, 0, stream>>>(
      (const unsigned short*)pooled, (const unsigned short*)bw1, P,
      800, 1024, 12544, 896);
  k_bias_relu<bf16, true><<<800, 256, 0, stream>>>(P, fc1_b, x1, 819200, 1024);

  // FC2: K=1024, KS=8 (KC=128, 2 steps). XCD-pinned grid: 448 blocks,
  // one z per XCD, no idle pads.
  k_gemm_bb<<<448, 256, 0, stream>>>(
      (const unsigned short*)x1, (const unsigned short*)bw2, P,
      800, 1024, 1024, 128);
  k_bias_relu<float, false><<<800, 256, 0, stream>>>(P, fc2_b, x2, 819200, 1024);

  k_heads<<<800, 640, 0, stream>>>(x2, cls_w, cls_b, bbox_w, bbox_b, (float*)d_out);
}

// Round 8
// 357.828 us; speedup vs baseline: 1.0244x; 1.0244x over previous
//
#include <hip/hip_runtime.h>
#include <hip/hip_bf16.h>

using bf16 = __hip_bfloat16;

typedef __attribute__((ext_vector_type(8))) short bf16x8;
typedef __attribute__((ext_vector_type(4))) float f32x4;

// async global->LDS, 16 B per lane, wave-uniform LDS base (+lane*16 by HW).
__device__ __forceinline__ void async16(const void* g, void* l) {
  __builtin_amdgcn_global_load_lds(
      (const __attribute__((address_space(1))) unsigned int*)g,
      (__attribute__((address_space(3))) unsigned int*)l, 16, 0, 0);
}

__device__ __forceinline__ void store_o(float* C, size_t i, float v) { C[i] = v; }
__device__ __forceinline__ void store_o(bf16* C, size_t i, float v) {
  C[i] = __float2bfloat16(v);
}

// ---------------------------------------------------------------------------
// K1: backbone conv (3->256, 3x3, stride16, pad1) fused with 2x2 avgpool.
// REWRITE: 2048 blocks x 4 x-positions. Weights staged to LDS once per block
// (27 coalesced 1KB loads; old code did 27 lane-stride-108B loads = ~64-way
// transaction split per load). Patches staged cooperatively; compute reads
// them as LDS broadcasts (free). Per-thread: 432 FMA (the VALU floor).
// ---------------------------------------------------------------------------
__global__ __launch_bounds__(256) void k_backbone(const float* __restrict__ img,
    const float* __restrict__ w, const float* __restrict__ bias,
    float* __restrict__ f) {
  __shared__ float wlds[6912];    // 256 cout x 27
  __shared__ float patch[432];    // [p(4)][sub(4)][cin*9+ky*3+kx(27)]
  int blk = blockIdx.x;           // 2048 = b(8) * y(32) * xq(8)
  int xq = blk & 7, y = (blk >> 3) & 31, b = blk >> 8;
  int x0 = xq * 4;
  int t = threadIdx.x;
  for (int i = t; i < 6912; i += 256) wlds[i] = w[i];
  for (int i = t; i < 432; i += 256) {
    int k27 = i % 27, r = i / 27;        // r = p*4 + sub
    int sub = r & 3, p = r >> 2;
    int kx = k27 % 3, ky = (k27 / 3) % 3, cin = k27 / 9;
    int sy = sub >> 1, sx = sub & 1;
    int iy = (2 * y + sy) * 16 - 1 + ky;           // max 1009 < 1024
    int ix = (2 * (x0 + p) + sx) * 16 - 1 + kx;
    float v = 0.f;
    if (iy >= 0 && ix >= 0)
      v = img[((size_t)(b * 3 + cin) * 1024 + iy) * 1024 + ix];
    patch[i] = v;
  }
  __syncthreads();
  int c = t;
  float wr[27];
#pragma unroll
  for (int k = 0; k < 27; ++k) wr[k] = wlds[c * 27 + k];   // stride-27: 2/bank
  float bs = bias[c];
#pragma unroll
  for (int p = 0; p < 4; ++p) {
    float acc = 0.f;
#pragma unroll
    for (int sub = 0; sub < 4; ++sub)
#pragma unroll
      for (int k = 0; k < 27; ++k)
        acc += patch[(p * 4 + sub) * 27 + k] * wr[k];      // broadcast read
    f[(size_t)((b * 32 + y) * 32 + x0 + p) * 256 + c] = acc * 0.25f + bs;
  }
}

// ---------------------------------------------------------------------------
// K2a: RPN conv partials. grid (pos=32, kc=16), thread = cout.
// ---------------------------------------------------------------------------
__global__ __launch_bounds__(256) void k_rpn(const float* __restrict__ f,
    const float* __restrict__ rpn_w, float* __restrict__ part) {
  int p = blockIdx.x;        // 0..31 : b*4 + x
  int kc = blockIdx.y;       // 0..15 : 16-cin chunk
  int x = p & 3, b = p >> 2;
  __shared__ float fpl[6][16];   // [row*3+col][cin2]
  int tid = threadIdx.x;
  if (tid < 96) {
    int cin2 = tid & 15;
    int rc = tid >> 4;       // 0..5 = row*3+col
    int row = rc / 3, col = rc % 3;
    int xc = x - 1 + col;    // <= 5, always < 32
    float v = 0.f;
    if (xc >= 0)
      v = f[((size_t)(b * 32 + row) * 32 + xc) * 256 + kc * 16 + cin2];
    fpl[rc][cin2] = v;
  }
  __syncthreads();
  int c = tid;
  const float* wbase = rpn_w + (size_t)c * 2304 + kc * 144;
  float acc = 0.f;
#pragma unroll
  for (int cin2 = 0; cin2 < 16; ++cin2) {
    const float* wp = wbase + cin2 * 9;
    acc += fpl[0][cin2] * wp[3] + fpl[1][cin2] * wp[4]
         + fpl[2][cin2] * wp[5] + fpl[3][cin2] * wp[6]
         + fpl[4][cin2] * wp[7] + fpl[5][cin2] * wp[8];
  }
  part[((size_t)kc * 32 + p) * 256 + c] = acc;
}

// ---------------------------------------------------------------------------
// K2b: reduce partials + ReLU, delta conv (2 threads per output), decode.
// ---------------------------------------------------------------------------
__global__ __launch_bounds__(512) void k_delta(const float* __restrict__ part,
    const float* __restrict__ rpn_b,
    const float* __restrict__ dw, const float* __restrict__ db,
    float* __restrict__ boxes) {
  int p = blockIdx.x;        // 0..31
  int x = p & 3, b = p >> 2;
  __shared__ float tbuf[256];
  __shared__ float dvals[135];
  int tid = threadIdx.x;
  if (tid < 256) {
    float s = rpn_b[tid];
#pragma unroll
    for (int kc = 0; kc < 16; ++kc)
      s += part[((size_t)kc * 32 + p) * 256 + tid];
    tbuf[tid] = fmaxf(s, 0.f);
  }
  __syncthreads();
  if (tid < 270) {
    int o = tid >> 1, half = tid & 1;
    const float* wp = dw + (size_t)o * 256 + half * 128;
    const float* tp = tbuf + half * 128;
    float s = 0.f;
#pragma unroll 8
    for (int k = 0; k < 128; ++k) s += tp[k] * wp[k];
    s += __shfl_xor(s, 1, 64);   // pair (2o, 2o+1) always within one wave
    if (half == 0) dvals[o] = s + db[o];
  }
  __syncthreads();
  if (tid < 27) {
    int i = x * 27 + tid;
    if (i < 100) {
      int a = tid;
      int si = a / 9, ri = (a / 3) % 3, ai = a % 3;
      float scale = 32.f * (float)(1 << si);
      float sr = (ri == 0) ? 0.70710678118654752f : (ri == 1 ? 1.0f : 1.41421356237309505f);
      float aw = scale * sr, ah = scale / sr;
      float aang = 45.f * (float)ai;
      float acx = 32.f * (float)x, acy = 0.f;
      float* bx = boxes + (size_t)(b * 100 + i) * 5;
      bx[0] = dvals[a * 5 + 0] * aw + acx;
      bx[1] = dvals[a * 5 + 1] * ah + acy;
      bx[2] = expf(dvals[a * 5 + 2]) * aw;
      bx[3] = expf(dvals[a * 5 + 3]) * ah;
      bx[4] = aang + dvals[a * 5 + 4];
    }
  }
}

// ---------------------------------------------------------------------------
// K3: rotated ROI align. 800 blocks, thread=channel; writes pooled as bf16
// in (n, c*49+bin) order. Bin loop: unconditional clamped gathers with
// zeroed OOB weights (branch-free) + unroll-7 -> ~28 loads in flight.
// ---------------------------------------------------------------------------
__global__ __launch_bounds__(256) void k_roialign(const float* __restrict__ f,
    const float* __restrict__ boxes, bf16* __restrict__ pooled) {
  int n = blockIdx.x;
  int b = n / 100;
  __shared__ int six[49], siy[49];
  __shared__ float swx[49], swy[49];
  __shared__ float pool_s[12544];
  int tid = threadIdx.x;
  if (tid < 49) {
    float cx = boxes[n * 5 + 0], cy = boxes[n * 5 + 1];
    float w = boxes[n * 5 + 2], h = boxes[n * 5 + 3], ang = boxes[n * 5 + 4];
    float ar = -ang * 0.017453292519943295f;
    float cc = cosf(ar), ss = sinf(ar);
    float t00 = w * (1.f / 32.f) * cc, t01 = -h * (1.f / 32.f) * ss;
    float t02 = cx * (2.f / 32.f) - 1.f;
    float t10 = w * (1.f / 32.f) * ss, t11 = h * (1.f / 32.f) * cc;
    float t12 = cy * (2.f / 32.f) - 1.f;
    int py = tid / 7, px = tid - py * 7;
    float lx = (2.f * px + 1.f) * (1.f / 7.f) - 1.f;
    float ly = (2.f * py + 1.f) * (1.f / 7.f) - 1.f;
    float gx = t00 * lx + t01 * ly + t02;
    float gy = t10 * lx + t11 * ly + t12;
    float ix = ((gx + 1.f) * 32.f - 1.f) * 0.5f;
    float iy = ((gy + 1.f) * 32.f - 1.f) * 0.5f;
    float x0 = floorf(ix), y0 = floorf(iy);
    six[tid] = (int)x0; siy[tid] = (int)y0;
    swx[tid] = ix - x0; swy[tid] = iy - y0;
  }
  __syncthreads();
  const float* fb = f + (size_t)b * 262144;
  int c = tid;
#pragma unroll 7
  for (int bin = 0; bin < 49; ++bin) {
    int x0 = six[bin], y0 = siy[bin];
    float wx = swx[bin], wy = swy[bin];
    bool x0ok = (x0 >= 0) & (x0 < 32), x1ok = (x0 + 1 >= 0) & (x0 + 1 < 32);
    bool y0ok = (y0 >= 0) & (y0 < 32), y1ok = (y0 + 1 >= 0) & (y0 + 1 < 32);
    int x0c = min(max(x0, 0), 31), x1c = min(max(x0 + 1, 0), 31);
    int y0c = min(max(y0, 0), 31), y1c = min(max(y0 + 1, 0), 31);
    float w00 = (x0ok && y0ok) ? (1.f - wx) * (1.f - wy) : 0.f;
    float w01 = (x1ok && y0ok) ? wx * (1.f - wy) : 0.f;
    float w10 = (x0ok && y1ok) ? (1.f - wx) * wy : 0.f;
    float w11 = (x1ok && y1ok) ? wx * wy : 0.f;
    float acc = fb[(y0c * 32 + x0c) * 256 + c] * w00
              + fb[(y0c * 32 + x1c) * 256 + c] * w01
              + fb[(y1c * 32 + x0c) * 256 + c] * w10
              + fb[(y1c * 32 + x1c) * 256 + c] * w11;
    pool_s[c * 49 + bin] = acc;
  }
  __syncthreads();
  bf16* po = pooled + (size_t)n * 12544;
  for (int k = tid; k < 12544; k += 256) po[k] = __float2bfloat16(pool_s[k]);
}

// ---------------------------------------------------------------------------
// K-cvtz: merged: fc1_w fp32->bf16, fc2_w fp32->bf16, zero P. One launch.
// ---------------------------------------------------------------------------
__device__ __forceinline__ unsigned int pk2(float a, float b) {
  unsigned int ua = __bfloat16_as_ushort(__float2bfloat16(a));
  unsigned int ub = __bfloat16_as_ushort(__float2bfloat16(b));
  return ua | (ub << 16);
}
__global__ __launch_bounds__(256) void k_cvtz(const float* __restrict__ s1,
    const float* __restrict__ s2, uint2* __restrict__ d1,
    uint2* __restrict__ d2, f32x4* __restrict__ Pz) {
  const int N1 = 3211264;   // fc1_w float4s (1024*12544/4)
  const int N2 = 262144;    // fc2_w float4s (1024*1024/4)
  const int NZ = 204800;    // P float4s (800*1024/4)
  int stride = gridDim.x * 256;
  for (int j = blockIdx.x * 256 + threadIdx.x; j < N1 + N2 + NZ; j += stride) {
    if (j < N1) {
      float4 v = ((const float4*)s1)[j];
      uint2 o; o.x = pk2(v.x, v.y); o.y = pk2(v.z, v.w);
      d1[j] = o;
    } else if (j < N1 + N2) {
      int i = j - N1;
      float4 v = ((const float4*)s2)[i];
      uint2 o; o.x = pk2(v.x, v.y); o.y = pk2(v.z, v.w);
      d2[i] = o;
    } else {
      Pz[j - N1 - N2] = (f32x4){0.f, 0.f, 0.f, 0.f};
    }
  }
}

// ---------------------------------------------------------------------------
// K4: both-bf16 split-K MFMA GEMM, counted-vmcnt double-buffer (T3+T4) +
// XCD-PINNED split-K (T1): all 56 tile-blocks of K-chunk z land on XCD z%8.
// Per-z working set ~3.3 MB fits one XCD's 4 MB L2 (R7: FETCH 92->25 MB).
// Tile 128x128, BK=64, 4 waves (2x2), 32 MFMA/wave/step, atomic accum.
// ---------------------------------------------------------------------------
__global__ __launch_bounds__(256) void k_gemm_bb(
    const unsigned short* __restrict__ A, const unsigned short* __restrict__ B,
    float* __restrict__ P, int M, int N, int K, int KC) {
  int b = blockIdx.x;
  int x8 = b & 7, j = b >> 3;
  int g = j / 56, t2 = j - g * 56;
  int z = x8 + 8 * g;
  int kbeg = z * KC;
  if (kbeg >= K) return;                   // idle padding block
  int kend = kbeg + KC; if (kend > K) kend = K;
  int n0 = (t2 & 7) * 128;                 // n-tile (N=1024 -> 8 tiles)
  int m0 = (t2 >> 3) * 128;                // m-tile (M=800  -> 7 tiles)

  __shared__ unsigned short As[2][128 * 64];  // 2 x 16 KB
  __shared__ unsigned short Bs[2][128 * 64];  // 2 x 16 KB
  int t = threadIdx.x;
  int wv = t >> 6, ln = t & 63;
  int quad = ln >> 4, l15 = ln & 15;
  int wm = wv >> 1, wn = wv & 1;           // 2x2 wave grid

  // Staging: lane (srow, sg): within-8-row-group row srow, global seg
  // sg = (ln&7)^srow lands at linear LDS slot (ln&7) -> XOR swizzle.
  int srow = ln >> 3;                      // 0..7
  int sg = (ln & 7) ^ srow;
  const unsigned short* Ap[4];
#pragma unroll
  for (int q = 0; q < 4; ++q) {
    int r = m0 + q * 32 + wv * 8 + srow;   // within-tile row & 7 == srow
    if (r > M - 1) r = M - 1;
    Ap[q] = A + (size_t)r * K + sg * 8;
  }
  const unsigned short* Bp[4];
#pragma unroll
  for (int c = 0; c < 4; ++c) {
    int r = n0 + wv * 32 + c * 8 + srow;   // N=1024: always in range
    Bp[c] = B + (size_t)r * K + sg * 8;
  }

  f32x4 acc[4][4];
#pragma unroll
  for (int mf = 0; mf < 4; ++mf)
#pragma unroll
    for (int nf = 0; nf < 4; ++nf) acc[mf][nf] = (f32x4){0.f, 0.f, 0.f, 0.f};

  // prologue: stage tile kbeg into buffer 0 (8 async16/wave, in flight)
#pragma unroll
  for (int q = 0; q < 4; ++q)
    async16(Ap[q] + kbeg, &As[0][q * 2048 + wv * 512]);
#pragma unroll
  for (int c = 0; c < 4; ++c)
    async16(Bp[c] + kbeg, &Bs[0][wv * 2048 + c * 512]);

  int cur = 0;
  for (int k0 = kbeg; k0 < kend; k0 += 64) {
    int k1 = k0 + 64;
    if (k1 < kend) {
      // stage next tile into buf^1 (that buffer's readers finished at the
      // barrier that ended the previous iteration -> WAR-safe).
#pragma unroll
      for (int q = 0; q < 4; ++q)
        async16(Ap[q] + k1, &As[cur ^ 1][q * 2048 + wv * 512]);
#pragma unroll
      for (int c = 0; c < 4; ++c)
        async16(Bp[c] + k1, &Bs[cur ^ 1][wv * 2048 + c * 512]);
      // wait for the OLD 8 only; the new 8 stay in flight across the barrier
      asm volatile("s_waitcnt vmcnt(8)" ::: "memory");
    } else {
      asm volatile("s_waitcnt vmcnt(0)" ::: "memory");
    }
    __builtin_amdgcn_s_barrier();          // all waves: buf[cur] resident
    __builtin_amdgcn_sched_barrier(0);
#pragma unroll
    for (int ks = 0; ks < 2; ++ks) {
      bf16x8 a[4];
#pragma unroll
      for (int mf = 0; mf < 4; ++mf) {
        int row = wm * 64 + mf * 16 + l15;           // row & 7 == l15 & 7
        a[mf] = *(const bf16x8*)&As[cur][row * 64 + (((ks * 4 + quad) ^ (l15 & 7)) * 8)];
      }
#pragma unroll
      for (int nf = 0; nf < 4; ++nf) {
        int brow = wn * 64 + nf * 16 + l15;
        bf16x8 b2 = *(const bf16x8*)&Bs[cur][brow * 64 + (((ks * 4 + quad) ^ (l15 & 7)) * 8)];
#pragma unroll
        for (int mf = 0; mf < 4; ++mf)
          acc[mf][nf] = __builtin_amdgcn_mfma_f32_16x16x32_bf16(a[mf], b2, acc[mf][nf], 0, 0, 0);
      }
    }
    __builtin_amdgcn_sched_barrier(0);
    asm volatile("" ::: "memory");
    __builtin_amdgcn_s_barrier();          // readers of buf[cur] done ->
    cur ^= 1;                              // next iter may restage into it
  }
  // atomic accumulate; D layout m = quad*4+r, n = l15 (within 16x16).
#pragma unroll
  for (int nf = 0; nf < 4; ++nf) {
    int n = n0 + wn * 64 + nf * 16 + l15;
#pragma unroll
    for (int mf = 0; mf < 4; ++mf) {
#pragma unroll
      for (int r = 0; r < 4; ++r) {
        int m = m0 + wm * 64 + mf * 16 + quad * 4 + r;
        if (m < M) atomicAdd(&P[(size_t)m * N + n], acc[mf][nf][r]);
      }
    }
  }
}

// ---------------------------------------------------------------------------
// K5: bias + ReLU epilogue: C = relu(P + bias). Optionally re-zeros P for
// the next atomic GEMM (saves a memset launch). float4-vectorized.
// ---------------------------------------------------------------------------
template <typename OutT, bool RZ>
__global__ __launch_bounds__(256) void k_bias_relu(float* __restrict__ P,
    const float* __restrict__ bias, OutT* __restrict__ C, int MN, int N) {
  int i = blockIdx.x * 256 + threadIdx.x;   // float4 index
  if (i * 4 >= MN) return;
  f32x4 s = *(const f32x4*)(P + (size_t)i * 4);
  int n = (i * 4) % N;
#pragma unroll
  for (int u = 0; u < 4; ++u)
    store_o(C, (size_t)i * 4 + u, fmaxf(s[u] + bias[n + u], 0.f));
  if (RZ) *(f32x4*)(P + (size_t)i * 4) = (f32x4){0.f, 0.f, 0.f, 0.f};
}

// ---------------------------------------------------------------------------
// K6: heads. One block per row, one wave per output (5 cls + 5 bbox).
// ---------------------------------------------------------------------------
__global__ __launch_bounds__(640) void k_heads(const float* __restrict__ x2,
    const float* __restrict__ cls_w, const float* __restrict__ cls_b,
    const float* __restrict__ bbox_w, const float* __restrict__ bbox_b,
    float* __restrict__ out) {
  int n = blockIdx.x;
  int wave = threadIdx.x >> 6;   // 0..9
  int lane = threadIdx.x & 63;
  const float* w = (wave < 5) ? (cls_w + (size_t)wave * 1024)
                              : (bbox_w + (size_t)(wave - 5) * 1024);
  const float* xr = x2 + (size_t)n * 1024;
  float s = 0.f;
  for (int k = lane; k < 1024; k += 64) s += xr[k] * w[k];
  for (int off = 32; off; off >>= 1) s += __shfl_down(s, off, 64);
  if (lane == 0) {
    int o = (wave < 5) ? wave : wave - 5;
    float bias = (wave < 5) ? cls_b[o] : bbox_b[o];
    int base = (wave < 5) ? 0 : 4000;
    out[base + n * 5 + o] = s + bias;
  }
}

// ---------------------------------------------------------------------------
extern "C" void kernel_launch(void* const* d_in, const int* in_sizes, int n_in,
                              void* d_out, int out_size, void* d_ws, size_t ws_size,
                              hipStream_t stream) {
  const float* images     = (const float*)d_in[0];
  const float* backbone_w = (const float*)d_in[1];
  const float* backbone_b = (const float*)d_in[2];
  const float* rpn_w      = (const float*)d_in[3];
  const float* rpn_b      = (const float*)d_in[4];
  // d_in[5]/d_in[6] (obj_w/obj_b): conv output unused by the reference.
  const float* delta_w    = (const float*)d_in[7];
  const float* delta_b    = (const float*)d_in[8];
  const float* fc1_w      = (const float*)d_in[9];
  const float* fc1_b      = (const float*)d_in[10];
  const float* fc2_w      = (const float*)d_in[11];
  const float* fc2_b      = (const float*)d_in[12];
  const float* cls_w      = (const float*)d_in[13];
  const float* cls_b      = (const float*)d_in[14];
  const float* bbox_w     = (const float*)d_in[15];
  const float* bbox_b     = (const float*)d_in[16];

  // Workspace layout (52.79 MB total; aliases are stream-ordered):
  //   bw1 @ 0          : 25,690,112 B (fc1_w bf16)  -- ALIASES f (8.39 MB,
  //                      dead after k_roialign; k_cvtz runs after it)
  //   boxes @25,690,112:     16,384 B
  //   pooled@25,706,496: 20,070,400 B -- ALIASES x2 (3.28 MB, written by FC2
  //                      bias_relu when pooled is dead)
  //   x1   @45,776,896 :  1,638,400 B
  //   P    @47,415,296 :  3,276,800 B (atomic accum; also rpn partials)
  //   bw2  @50,692,096 :  2,097,152 B (fc2_w bf16)
  char* ws = (char*)d_ws;
  bf16*  bw1    = (bf16*) ws;
  float* f      = (float*)ws;                  // phase-1 only
  float* boxes  = (float*)(ws + 25690112);
  bf16*  pooled = (bf16*) (ws + 25706496);
  float* x2     = (float*)(ws + 25706496);     // alias, phase-3
  bf16*  x1     = (bf16*) (ws + 45776896);
  float* P      = (float*)(ws + 47415296);
  bf16*  bw2    = (bf16*) (ws + 50692096);
  float* rpart  = P;

  k_backbone<<<2048, 256, 0, stream>>>(images, backbone_w, backbone_b, f);
  k_rpn<<<dim3(32, 16), 256, 0, stream>>>(f, rpn_w, rpart);
  k_delta<<<32, 512, 0, stream>>>(rpart, rpn_b, delta_w, delta_b, boxes);
  k_roialign<<<800, 256, 0, stream>>>(f, boxes, pooled);

  // merged: weight pre-conversion (f dead; bw1 overwrites) + zero P
  k_cvtz<<<2048, 256, 0, stream>>>(fc1_w, fc2_w, (uint2*)bw1, (uint2*)bw2,
                                   (f32x4*)P);

  // FC1: K=12544, KS=14 (KC=896, 14 steps). XCD-pinned grid: 896 blocks
  // (784 working + 112 idle pads so that XCD(b)=b%8 == z%8).
  k_gemm_bb<<<896, 256, 0, stream>>>(
      (const unsigned short*)pooled, (const unsigned short*)bw1, P,
      800, 1024, 12544, 896);
  k_bias_relu<bf16, true><<<800, 256, 0, stream>>>(P, fc1_b, x1, 819200, 1024);

  // FC2: K=1024, KS=8 (KC=128, 2 steps). XCD-pinned grid: 448 blocks,
  // one z per XCD, no idle pads.
  k_gemm_bb<<<448, 256, 0, stream>>>(
      (const unsigned short*)x1, (const unsigned short*)bw2, P,
      800, 1024, 1024, 128);
  k_bias_relu<float, false><<<800, 256, 0, stream>>>(P, fc2_b, x2, 819200, 1024);

  k_heads<<<800, 640, 0, stream>>>(x2, cls_w, cls_b, bbox_w, bbox_b, (float*)d_out);
}

// Round 9
// 356.996 us; speedup vs baseline: 1.0268x; 1.0023x over previous
//
#include <hip/hip_runtime.h>
#include <hip/hip_bf16.h>

using bf16 = __hip_bfloat16;

typedef __attribute__((ext_vector_type(8))) short bf16x8;
typedef __attribute__((ext_vector_type(4))) float f32x4;

// async global->LDS, 16 B per lane, wave-uniform LDS base (+lane*16 by HW).
__device__ __forceinline__ void async16(const void* g, void* l) {
  __builtin_amdgcn_global_load_lds(
      (const __attribute__((address_space(1))) unsigned int*)g,
      (__attribute__((address_space(3))) unsigned int*)l, 16, 0, 0);
}

__device__ __forceinline__ void store_o(float* C, size_t i, float v) { C[i] = v; }
__device__ __forceinline__ void store_o(bf16* C, size_t i, float v) {
  C[i] = __float2bfloat16(v);
}

__device__ __forceinline__ unsigned int pk2(float a, float b) {
  unsigned int ua = __bfloat16_as_ushort(__float2bfloat16(a));
  unsigned int ub = __bfloat16_as_ushort(__float2bfloat16(b));
  return ua | (ub << 16);
}

// ---------------------------------------------------------------------------
// K1: backbone conv (3->256, 3x3, stride16, pad1) fused with 2x2 avgpool.
// 2048 blocks x 4 x-positions; weights staged to LDS once per block.
// ---------------------------------------------------------------------------
__global__ __launch_bounds__(256) void k_backbone(const float* __restrict__ img,
    const float* __restrict__ w, const float* __restrict__ bias,
    float* __restrict__ f) {
  __shared__ float wlds[6912];    // 256 cout x 27
  __shared__ float patch[432];    // [p(4)][sub(4)][cin*9+ky*3+kx(27)]
  int blk = blockIdx.x;           // 2048 = b(8) * y(32) * xq(8)
  int xq = blk & 7, y = (blk >> 3) & 31, b = blk >> 8;
  int x0 = xq * 4;
  int t = threadIdx.x;
  for (int i = t; i < 6912; i += 256) wlds[i] = w[i];
  for (int i = t; i < 432; i += 256) {
    int k27 = i % 27, r = i / 27;        // r = p*4 + sub
    int sub = r & 3, p = r >> 2;
    int kx = k27 % 3, ky = (k27 / 3) % 3, cin = k27 / 9;
    int sy = sub >> 1, sx = sub & 1;
    int iy = (2 * y + sy) * 16 - 1 + ky;           // max 1009 < 1024
    int ix = (2 * (x0 + p) + sx) * 16 - 1 + kx;
    float v = 0.f;
    if (iy >= 0 && ix >= 0)
      v = img[((size_t)(b * 3 + cin) * 1024 + iy) * 1024 + ix];
    patch[i] = v;
  }
  __syncthreads();
  int c = t;
  float wr[27];
#pragma unroll
  for (int k = 0; k < 27; ++k) wr[k] = wlds[c * 27 + k];   // stride-27: 2/bank
  float bs = bias[c];
#pragma unroll
  for (int p = 0; p < 4; ++p) {
    float acc = 0.f;
#pragma unroll
    for (int sub = 0; sub < 4; ++sub)
#pragma unroll
      for (int k = 0; k < 27; ++k)
        acc += patch[(p * 4 + sub) * 27 + k] * wr[k];      // broadcast read
    f[(size_t)((b * 32 + y) * 32 + x0 + p) * 256 + c] = acc * 0.25f + bs;
  }
}

// ---------------------------------------------------------------------------
// K2a: RPN conv partials. grid (pos=32, kc=16), thread = cout.
// ---------------------------------------------------------------------------
__global__ __launch_bounds__(256) void k_rpn(const float* __restrict__ f,
    const float* __restrict__ rpn_w, float* __restrict__ part) {
  int p = blockIdx.x;        // 0..31 : b*4 + x
  int kc = blockIdx.y;       // 0..15 : 16-cin chunk
  int x = p & 3, b = p >> 2;
  __shared__ float fpl[6][16];   // [row*3+col][cin2]
  int tid = threadIdx.x;
  if (tid < 96) {
    int cin2 = tid & 15;
    int rc = tid >> 4;       // 0..5 = row*3+col
    int row = rc / 3, col = rc % 3;
    int xc = x - 1 + col;    // <= 5, always < 32
    float v = 0.f;
    if (xc >= 0)
      v = f[((size_t)(b * 32 + row) * 32 + xc) * 256 + kc * 16 + cin2];
    fpl[rc][cin2] = v;
  }
  __syncthreads();
  int c = tid;
  const float* wbase = rpn_w + (size_t)c * 2304 + kc * 144;
  float acc = 0.f;
#pragma unroll
  for (int cin2 = 0; cin2 < 16; ++cin2) {
    const float* wp = wbase + cin2 * 9;
    acc += fpl[0][cin2] * wp[3] + fpl[1][cin2] * wp[4]
         + fpl[2][cin2] * wp[5] + fpl[3][cin2] * wp[6]
         + fpl[4][cin2] * wp[7] + fpl[5][cin2] * wp[8];
  }
  part[((size_t)kc * 32 + p) * 256 + c] = acc;
}

// ---------------------------------------------------------------------------
// K2b: reduce partials + ReLU, delta conv (2 threads/output, 4-way ILP).
// ---------------------------------------------------------------------------
__global__ __launch_bounds__(512) void k_delta(const float* __restrict__ part,
    const float* __restrict__ rpn_b,
    const float* __restrict__ dw, const float* __restrict__ db,
    float* __restrict__ boxes) {
  int p = blockIdx.x;        // 0..31
  int x = p & 3, b = p >> 2;
  __shared__ float tbuf[256];
  __shared__ float dvals[135];
  int tid = threadIdx.x;
  if (tid < 256) {
    float s = rpn_b[tid];
#pragma unroll
    for (int kc = 0; kc < 16; ++kc)
      s += part[((size_t)kc * 32 + p) * 256 + tid];
    tbuf[tid] = fmaxf(s, 0.f);
  }
  __syncthreads();
  if (tid < 270) {
    int o = tid >> 1, half = tid & 1;
    const float* wp = dw + (size_t)o * 256 + half * 128;
    const float* tp = tbuf + half * 128;
    float s0 = 0.f, s1 = 0.f, s2 = 0.f, s3 = 0.f;
#pragma unroll 8
    for (int k = 0; k < 128; k += 4) {
      s0 += tp[k]     * wp[k];
      s1 += tp[k + 1] * wp[k + 1];
      s2 += tp[k + 2] * wp[k + 2];
      s3 += tp[k + 3] * wp[k + 3];
    }
    float s = (s0 + s1) + (s2 + s3);
    s += __shfl_xor(s, 1, 64);   // pair (2o, 2o+1) always within one wave
    if (half == 0) dvals[o] = s + db[o];
  }
  __syncthreads();
  if (tid < 27) {
    int i = x * 27 + tid;
    if (i < 100) {
      int a = tid;
      int si = a / 9, ri = (a / 3) % 3, ai = a % 3;
      float scale = 32.f * (float)(1 << si);
      float sr = (ri == 0) ? 0.70710678118654752f : (ri == 1 ? 1.0f : 1.41421356237309505f);
      float aw = scale * sr, ah = scale / sr;
      float aang = 45.f * (float)ai;
      float acx = 32.f * (float)x, acy = 0.f;
      float* bx = boxes + (size_t)(b * 100 + i) * 5;
      bx[0] = dvals[a * 5 + 0] * aw + acx;
      bx[1] = dvals[a * 5 + 1] * ah + acy;
      bx[2] = expf(dvals[a * 5 + 2]) * aw;
      bx[3] = expf(dvals[a * 5 + 3]) * ah;
      bx[4] = aang + dvals[a * 5 + 4];
    }
  }
}

// ---------------------------------------------------------------------------
// K3: rotated ROI align. Branch-free clamped gathers, unroll-7; pooled
// store vectorized 8B/lane (packed bf16 pairs).
// ---------------------------------------------------------------------------
__global__ __launch_bounds__(256) void k_roialign(const float* __restrict__ f,
    const float* __restrict__ boxes, bf16* __restrict__ pooled) {
  int n = blockIdx.x;
  int b = n / 100;
  __shared__ int six[49], siy[49];
  __shared__ float swx[49], swy[49];
  __shared__ float pool_s[12544];
  int tid = threadIdx.x;
  if (tid < 49) {
    float cx = boxes[n * 5 + 0], cy = boxes[n * 5 + 1];
    float w = boxes[n * 5 + 2], h = boxes[n * 5 + 3], ang = boxes[n * 5 + 4];
    float ar = -ang * 0.017453292519943295f;
    float cc = cosf(ar), ss = sinf(ar);
    float t00 = w * (1.f / 32.f) * cc, t01 = -h * (1.f / 32.f) * ss;
    float t02 = cx * (2.f / 32.f) - 1.f;
    float t10 = w * (1.f / 32.f) * ss, t11 = h * (1.f / 32.f) * cc;
    float t12 = cy * (2.f / 32.f) - 1.f;
    int py = tid / 7, px = tid - py * 7;
    float lx = (2.f * px + 1.f) * (1.f / 7.f) - 1.f;
    float ly = (2.f * py + 1.f) * (1.f / 7.f) - 1.f;
    float gx = t00 * lx + t01 * ly + t02;
    float gy = t10 * lx + t11 * ly + t12;
    float ix = ((gx + 1.f) * 32.f - 1.f) * 0.5f;
    float iy = ((gy + 1.f) * 32.f - 1.f) * 0.5f;
    float x0 = floorf(ix), y0 = floorf(iy);
    six[tid] = (int)x0; siy[tid] = (int)y0;
    swx[tid] = ix - x0; swy[tid] = iy - y0;
  }
  __syncthreads();
  const float* fb = f + (size_t)b * 262144;
  int c = tid;
#pragma unroll 7
  for (int bin = 0; bin < 49; ++bin) {
    int x0 = six[bin], y0 = siy[bin];
    float wx = swx[bin], wy = swy[bin];
    bool x0ok = (x0 >= 0) & (x0 < 32), x1ok = (x0 + 1 >= 0) & (x0 + 1 < 32);
    bool y0ok = (y0 >= 0) & (y0 < 32), y1ok = (y0 + 1 >= 0) & (y0 + 1 < 32);
    int x0c = min(max(x0, 0), 31), x1c = min(max(x0 + 1, 0), 31);
    int y0c = min(max(y0, 0), 31), y1c = min(max(y0 + 1, 0), 31);
    float w00 = (x0ok && y0ok) ? (1.f - wx) * (1.f - wy) : 0.f;
    float w01 = (x1ok && y0ok) ? wx * (1.f - wy) : 0.f;
    float w10 = (x0ok && y1ok) ? (1.f - wx) * wy : 0.f;
    float w11 = (x1ok && y1ok) ? wx * wy : 0.f;
    float acc = fb[(y0c * 32 + x0c) * 256 + c] * w00
              + fb[(y0c * 32 + x1c) * 256 + c] * w01
              + fb[(y1c * 32 + x0c) * 256 + c] * w10
              + fb[(y1c * 32 + x1c) * 256 + c] * w11;
    pool_s[c * 49 + bin] = acc;
  }
  __syncthreads();
  uint2* po = (uint2*)(pooled + (size_t)n * 12544);   // 3136 x 8B
  for (int k = tid; k < 3136; k += 256) {
    f32x4 v = *(const f32x4*)&pool_s[k * 4];
    uint2 o; o.x = pk2(v[0], v[1]); o.y = pk2(v[2], v[3]);
    po[k] = o;
  }
}

// ---------------------------------------------------------------------------
// K-cvtz: merged: fc1_w fp32->bf16, fc2_w fp32->bf16, zero P. One launch.
// ---------------------------------------------------------------------------
__global__ __launch_bounds__(256) void k_cvtz(const float* __restrict__ s1,
    const float* __restrict__ s2, uint2* __restrict__ d1,
    uint2* __restrict__ d2, f32x4* __restrict__ Pz) {
  const int N1 = 3211264;   // fc1_w float4s (1024*12544/4)
  const int N2 = 262144;    // fc2_w float4s (1024*1024/4)
  const int NZ = 204800;    // P float4s (800*1024/4)
  int stride = gridDim.x * 256;
  for (int j = blockIdx.x * 256 + threadIdx.x; j < N1 + N2 + NZ; j += stride) {
    if (j < N1) {
      float4 v = ((const float4*)s1)[j];
      uint2 o; o.x = pk2(v.x, v.y); o.y = pk2(v.z, v.w);
      d1[j] = o;
    } else if (j < N1 + N2) {
      int i = j - N1;
      float4 v = ((const float4*)s2)[i];
      uint2 o; o.x = pk2(v.x, v.y); o.y = pk2(v.z, v.w);
      d2[i] = o;
    } else {
      Pz[j - N1 - N2] = (f32x4){0.f, 0.f, 0.f, 0.f};
    }
  }
}

// ---------------------------------------------------------------------------
// K4: both-bf16 split-K MFMA GEMM, counted-vmcnt double-buffer (T3+T4) +
// XCD-pinned split-K (T1). z = zmul*(blockIdx&7) + zoff, so a launch can
// cover even/odd K-chunks (FC1 split for profiling visibility) while
// keeping all 56 tile-blocks of a chunk on one XCD (R7: FETCH 92->25 MB).
// Tile 128x128, BK=64, 4 waves (2x2), 32 MFMA/wave/step, atomic accum.
// grid = 448 (8 xcd x 56 tiles); blocks with z*KC >= K exit.
// ---------------------------------------------------------------------------
__global__ __launch_bounds__(256) void k_gemm_bb(
    const unsigned short* __restrict__ A, const unsigned short* __restrict__ B,
    float* __restrict__ P, int M, int N, int K, int KC, int zmul, int zoff) {
  int b = blockIdx.x;
  int xcd = b & 7, t2 = b >> 3;            // t2 in 0..55
  int z = zmul * xcd + zoff;
  int kbeg = z * KC;
  if (kbeg >= K) return;                   // idle padding block
  int kend = kbeg + KC; if (kend > K) kend = K;
  int n0 = (t2 & 7) * 128;                 // n-tile (N=1024 -> 8 tiles)
  int m0 = (t2 >> 3) * 128;                // m-tile (M=800  -> 7 tiles)

  __shared__ unsigned short As[2][128 * 64];  // 2 x 16 KB
  __shared__ unsigned short Bs[2][128 * 64];  // 2 x 16 KB
  int t = threadIdx.x;
  int wv = t >> 6, ln = t & 63;
  int quad = ln >> 4, l15 = ln & 15;
  int wm = wv >> 1, wn = wv & 1;           // 2x2 wave grid

  // Staging: lane (srow, sg): within-8-row-group row srow, global seg
  // sg = (ln&7)^srow lands at linear LDS slot (ln&7) -> XOR swizzle.
  int srow = ln >> 3;                      // 0..7
  int sg = (ln & 7) ^ srow;
  const unsigned short* Ap[4];
#pragma unroll
  for (int q = 0; q < 4; ++q) {
    int r = m0 + q * 32 + wv * 8 + srow;   // within-tile row & 7 == srow
    if (r > M - 1) r = M - 1;
    Ap[q] = A + (size_t)r * K + sg * 8;
  }
  const unsigned short* Bp[4];
#pragma unroll
  for (int c = 0; c < 4; ++c) {
    int r = n0 + wv * 32 + c * 8 + srow;   // N=1024: always in range
    Bp[c] = B + (size_t)r * K + sg * 8;
  }

  f32x4 acc[4][4];
#pragma unroll
  for (int mf = 0; mf < 4; ++mf)
#pragma unroll
    for (int nf = 0; nf < 4; ++nf) acc[mf][nf] = (f32x4){0.f, 0.f, 0.f, 0.f};

  // prologue: stage tile kbeg into buffer 0 (8 async16/wave, in flight)
#pragma unroll
  for (int q = 0; q < 4; ++q)
    async16(Ap[q] + kbeg, &As[0][q * 2048 + wv * 512]);
#pragma unroll
  for (int c = 0; c < 4; ++c)
    async16(Bp[c] + kbeg, &Bs[0][wv * 2048 + c * 512]);

  int cur = 0;
  for (int k0 = kbeg; k0 < kend; k0 += 64) {
    int k1 = k0 + 64;
    if (k1 < kend) {
      // stage next tile into buf^1 (that buffer's readers finished at the
      // barrier that ended the previous iteration -> WAR-safe).
#pragma unroll
      for (int q = 0; q < 4; ++q)
        async16(Ap[q] + k1, &As[cur ^ 1][q * 2048 + wv * 512]);
#pragma unroll
      for (int c = 0; c < 4; ++c)
        async16(Bp[c] + k1, &Bs[cur ^ 1][wv * 2048 + c * 512]);
      // wait for the OLD 8 only; the new 8 stay in flight across the barrier
      asm volatile("s_waitcnt vmcnt(8)" ::: "memory");
    } else {
      asm volatile("s_waitcnt vmcnt(0)" ::: "memory");
    }
    __builtin_amdgcn_s_barrier();          // all waves: buf[cur] resident
    __builtin_amdgcn_sched_barrier(0);
#pragma unroll
    for (int ks = 0; ks < 2; ++ks) {
      bf16x8 a[4];
#pragma unroll
      for (int mf = 0; mf < 4; ++mf) {
        int row = wm * 64 + mf * 16 + l15;           // row & 7 == l15 & 7
        a[mf] = *(const bf16x8*)&As[cur][row * 64 + (((ks * 4 + quad) ^ (l15 & 7)) * 8)];
      }
#pragma unroll
      for (int nf = 0; nf < 4; ++nf) {
        int brow = wn * 64 + nf * 16 + l15;
        bf16x8 b2 = *(const bf16x8*)&Bs[cur][brow * 64 + (((ks * 4 + quad) ^ (l15 & 7)) * 8)];
#pragma unroll
        for (int mf = 0; mf < 4; ++mf)
          acc[mf][nf] = __builtin_amdgcn_mfma_f32_16x16x32_bf16(a[mf], b2, acc[mf][nf], 0, 0, 0);
      }
    }
    __builtin_amdgcn_sched_barrier(0);
    asm volatile("" ::: "memory");
    __builtin_amdgcn_s_barrier();          // readers of buf[cur] done ->
    cur ^= 1;                              // next iter may restage into it
  }
  // atomic accumulate; D layout m = quad*4+r, n = l15 (within 16x16).
#pragma unroll
  for (int nf = 0; nf < 4; ++nf) {
    int n = n0 + wn * 64 + nf * 16 + l15;
#pragma unroll
    for (int mf = 0; mf < 4; ++mf) {
#pragma unroll
      for (int r = 0; r < 4; ++r) {
        int m = m0 + wm * 64 + mf * 16 + quad * 4 + r;
        if (m < M) atomicAdd(&P[(size_t)m * N + n], acc[mf][nf][r]);
      }
    }
  }
}

// ---------------------------------------------------------------------------
// K5: bias + ReLU epilogue: C = relu(P + bias); re-zeros P for the next
// atomic GEMM. float4-vectorized.
// ---------------------------------------------------------------------------
template <typename OutT, bool RZ>
__global__ __launch_bounds__(256) void k_bias_relu(float* __restrict__ P,
    const float* __restrict__ bias, OutT* __restrict__ C, int MN, int N) {
  int i = blockIdx.x * 256 + threadIdx.x;   // float4 index
  if (i * 4 >= MN) return;
  f32x4 s = *(const f32x4*)(P + (size_t)i * 4);
  int n = (i * 4) % N;
#pragma unroll
  for (int u = 0; u < 4; ++u)
    store_o(C, (size_t)i * 4 + u, fmaxf(s[u] + bias[n + u], 0.f));
  if (RZ) *(f32x4*)(P + (size_t)i * 4) = (f32x4){0.f, 0.f, 0.f, 0.f};
}

// ---------------------------------------------------------------------------
// K6: heads FUSED with FC2 epilogue: x2row = relu(P[n] + fc2_b) built in
// LDS, then one wave per output (5 cls + 5 bbox). Drops the x2 buffer and
// one kernel launch.
// ---------------------------------------------------------------------------
__global__ __launch_bounds__(640) void k_heads(const float* __restrict__ P,
    const float* __restrict__ fc2_b,
    const float* __restrict__ cls_w, const float* __restrict__ cls_b,
    const float* __restrict__ bbox_w, const float* __restrict__ bbox_b,
    float* __restrict__ out) {
  __shared__ float xr[1024];
  int n = blockIdx.x;
  for (int i = threadIdx.x; i < 1024; i += 640)
    xr[i] = fmaxf(P[(size_t)n * 1024 + i] + fc2_b[i], 0.f);
  __syncthreads();
  int wave = threadIdx.x >> 6;   // 0..9
  int lane = threadIdx.x & 63;
  const float* w = (wave < 5) ? (cls_w + (size_t)wave * 1024)
                              : (bbox_w + (size_t)(wave - 5) * 1024);
  float s = 0.f;
  for (int k = lane; k < 1024; k += 64) s += xr[k] * w[k];
  for (int off = 32; off; off >>= 1) s += __shfl_down(s, off, 64);
  if (lane == 0) {
    int o = (wave < 5) ? wave : wave - 5;
    float bias = (wave < 5) ? cls_b[o] : bbox_b[o];
    int base = (wave < 5) ? 0 : 4000;
    out[base + n * 5 + o] = s + bias;
  }
}

// ---------------------------------------------------------------------------
extern "C" void kernel_launch(void* const* d_in, const int* in_sizes, int n_in,
                              void* d_out, int out_size, void* d_ws, size_t ws_size,
                              hipStream_t stream) {
  const float* images     = (const float*)d_in[0];
  const float* backbone_w = (const float*)d_in[1];
  const float* backbone_b = (const float*)d_in[2];
  const float* rpn_w      = (const float*)d_in[3];
  const float* rpn_b      = (const float*)d_in[4];
  // d_in[5]/d_in[6] (obj_w/obj_b): conv output unused by the reference.
  const float* delta_w    = (const float*)d_in[7];
  const float* delta_b    = (const float*)d_in[8];
  const float* fc1_w      = (const float*)d_in[9];
  const float* fc1_b      = (const float*)d_in[10];
  const float* fc2_w      = (const float*)d_in[11];
  const float* fc2_b      = (const float*)d_in[12];
  const float* cls_w      = (const float*)d_in[13];
  const float* cls_b      = (const float*)d_in[14];
  const float* bbox_w     = (const float*)d_in[15];
  const float* bbox_b     = (const float*)d_in[16];

  // Workspace layout (49.5 MB; aliases stream-ordered):
  //   bw1 @ 0          : 25,690,112 B (fc1_w bf16)  -- ALIASES f (8.39 MB,
  //                      dead after k_roialign; k_cvtz runs after it)
  //   boxes @25,690,112:     16,384 B
  //   pooled@25,706,496: 20,070,400 B
  //   x1   @45,776,896 :  1,638,400 B
  //   P    @47,415,296 :  3,276,800 B (atomic accum; also rpn partials;
  //                      heads reads FC2 result from here — x2 eliminated)
  //   bw2  @50,692,096 :  2,097,152 B (fc2_w bf16)
  char* ws = (char*)d_ws;
  bf16*  bw1    = (bf16*) ws;
  float* f      = (float*)ws;                  // phase-1 only
  float* boxes  = (float*)(ws + 25690112);
  bf16*  pooled = (bf16*) (ws + 25706496);
  bf16*  x1     = (bf16*) (ws + 45776896);
  float* P      = (float*)(ws + 47415296);
  bf16*  bw2    = (bf16*) (ws + 50692096);
  float* rpart  = P;

  k_backbone<<<2048, 256, 0, stream>>>(images, backbone_w, backbone_b, f);
  k_rpn<<<dim3(32, 16), 256, 0, stream>>>(f, rpn_w, rpart);
  k_delta<<<32, 512, 0, stream>>>(rpart, rpn_b, delta_w, delta_b, boxes);
  k_roialign<<<800, 256, 0, stream>>>(f, boxes, pooled);

  // merged: weight pre-conversion (f dead; bw1 overwrites) + zero P
  k_cvtz<<<2048, 256, 0, stream>>>(fc1_w, fc2_w, (uint2*)bw1, (uint2*)bw2,
                                   (f32x4*)P);

  // FC1: K=12544, KS=14 (KC=896), split into even/odd z for profiling
  // visibility. Each launch: 448 blocks, z = 2*(b&7)+par, XCD-pinned.
  k_gemm_bb<<<448, 256, 0, stream>>>(
      (const unsigned short*)pooled, (const unsigned short*)bw1, P,
      800, 1024, 12544, 896, 2, 0);
  k_gemm_bb<<<448, 256, 0, stream>>>(
      (const unsigned short*)pooled, (const unsigned short*)bw1, P,
      800, 1024, 12544, 896, 2, 1);
  k_bias_relu<bf16, true><<<800, 256, 0, stream>>>(P, fc1_b, x1, 819200, 1024);

  // FC2: K=1024, KS=8 (KC=128), one z per XCD.
  k_gemm_bb<<<448, 256, 0, stream>>>(
      (const unsigned short*)x1, (const unsigned short*)bw2, P,
      800, 1024, 1024, 128, 1, 0);

  // heads fused with FC2 bias+relu (reads P directly)
  k_heads<<<800, 640, 0, stream>>>(P, fc2_b, cls_w, cls_b, bbox_w, bbox_b,
                                   (float*)d_out);
}

// Round 10
// 349.946 us; speedup vs baseline: 1.0475x; 1.0201x over previous
//
#include <hip/hip_runtime.h>
#include <hip/hip_bf16.h>

using bf16 = __hip_bfloat16;

typedef __attribute__((ext_vector_type(8))) short bf16x8;
typedef __attribute__((ext_vector_type(4))) float f32x4;

// async global->LDS, 16 B per lane, wave-uniform LDS base (+lane*16 by HW).
__device__ __forceinline__ void async16(const void* g, void* l) {
  __builtin_amdgcn_global_load_lds(
      (const __attribute__((address_space(1))) unsigned int*)g,
      (__attribute__((address_space(3))) unsigned int*)l, 16, 0, 0);
}

__device__ __forceinline__ void store_o(float* C, size_t i, float v) { C[i] = v; }
__device__ __forceinline__ void store_o(bf16* C, size_t i, float v) {
  C[i] = __float2bfloat16(v);
}

__device__ __forceinline__ unsigned int pk2(float a, float b) {
  unsigned int ua = __bfloat16_as_ushort(__float2bfloat16(a));
  unsigned int ub = __bfloat16_as_ushort(__float2bfloat16(b));
  return ua | (ub << 16);
}

// ---------------------------------------------------------------------------
// K1: backbone conv (3->256, 3x3, stride16, pad1) fused with 2x2 avgpool,
// PLUS 256 grid-partitioned aux blocks: fc2_w fp32->bf16 cvt + zero P.
// (Aux work is independent of backbone; fusing it removes a launch and
// overlaps its 6.4 MB of traffic with backbone's compute.)
// blocks 0..2047: backbone (4 x-positions each). blocks 2048..2303: aux.
// ---------------------------------------------------------------------------
__global__ __launch_bounds__(256) void k_backbone(const float* __restrict__ img,
    const float* __restrict__ w, const float* __restrict__ bias,
    float* __restrict__ f,
    const float* __restrict__ fc2w, uint2* __restrict__ bw2,
    f32x4* __restrict__ Pz) {
  int blk = blockIdx.x;
  if (blk >= 2048) {
    const int N2 = 262144;   // fc2_w float4s (1024*1024/4)
    const int NZ = 204800;   // P float4s (800*1024/4)
    int stride = 256 * 256;
    for (int j = (blk - 2048) * 256 + threadIdx.x; j < N2 + NZ; j += stride) {
      if (j < N2) {
        float4 v = ((const float4*)fc2w)[j];
        uint2 o; o.x = pk2(v.x, v.y); o.y = pk2(v.z, v.w);
        bw2[j] = o;
      } else {
        Pz[j - N2] = (f32x4){0.f, 0.f, 0.f, 0.f};
      }
    }
    return;
  }
  __shared__ float wlds[6912];    // 256 cout x 27
  __shared__ float patch[432];    // [p(4)][sub(4)][cin*9+ky*3+kx(27)]
  int xq = blk & 7, y = (blk >> 3) & 31, b = blk >> 8;
  int x0 = xq * 4;
  int t = threadIdx.x;
  for (int i = t; i < 6912; i += 256) wlds[i] = w[i];
  for (int i = t; i < 432; i += 256) {
    int k27 = i % 27, r = i / 27;        // r = p*4 + sub
    int sub = r & 3, p = r >> 2;
    int kx = k27 % 3, ky = (k27 / 3) % 3, cin = k27 / 9;
    int sy = sub >> 1, sx = sub & 1;
    int iy = (2 * y + sy) * 16 - 1 + ky;           // max 1009 < 1024
    int ix = (2 * (x0 + p) + sx) * 16 - 1 + kx;
    float v = 0.f;
    if (iy >= 0 && ix >= 0)
      v = img[((size_t)(b * 3 + cin) * 1024 + iy) * 1024 + ix];
    patch[i] = v;
  }
  __syncthreads();
  int c = t;
  float wr[27];
#pragma unroll
  for (int k = 0; k < 27; ++k) wr[k] = wlds[c * 27 + k];   // stride-27: 2/bank
  float bs = bias[c];
#pragma unroll
  for (int p = 0; p < 4; ++p) {
    float acc = 0.f;
#pragma unroll
    for (int sub = 0; sub < 4; ++sub)
#pragma unroll
      for (int k = 0; k < 27; ++k)
        acc += patch[(p * 4 + sub) * 27 + k] * wr[k];      // broadcast read
    f[(size_t)((b * 32 + y) * 32 + x0 + p) * 256 + c] = acc * 0.25f + bs;
  }
}

// ---------------------------------------------------------------------------
// K2a: RPN conv partials. grid (pos=32, kc=16), thread = cout.
// ---------------------------------------------------------------------------
__global__ __launch_bounds__(256) void k_rpn(const float* __restrict__ f,
    const float* __restrict__ rpn_w, float* __restrict__ part) {
  int p = blockIdx.x;        // 0..31 : b*4 + x
  int kc = blockIdx.y;       // 0..15 : 16-cin chunk
  int x = p & 3, b = p >> 2;
  __shared__ float fpl[6][16];   // [row*3+col][cin2]
  int tid = threadIdx.x;
  if (tid < 96) {
    int cin2 = tid & 15;
    int rc = tid >> 4;       // 0..5 = row*3+col
    int row = rc / 3, col = rc % 3;
    int xc = x - 1 + col;    // <= 5, always < 32
    float v = 0.f;
    if (xc >= 0)
      v = f[((size_t)(b * 32 + row) * 32 + xc) * 256 + kc * 16 + cin2];
    fpl[rc][cin2] = v;
  }
  __syncthreads();
  int c = tid;
  const float* wbase = rpn_w + (size_t)c * 2304 + kc * 144;
  float acc = 0.f;
#pragma unroll
  for (int cin2 = 0; cin2 < 16; ++cin2) {
    const float* wp = wbase + cin2 * 9;
    acc += fpl[0][cin2] * wp[3] + fpl[1][cin2] * wp[4]
         + fpl[2][cin2] * wp[5] + fpl[3][cin2] * wp[6]
         + fpl[4][cin2] * wp[7] + fpl[5][cin2] * wp[8];
  }
  part[((size_t)kc * 32 + p) * 256 + c] = acc;
}

// ---------------------------------------------------------------------------
// K2b: reduce partials + ReLU, delta conv (2 threads/output, 4-way ILP).
// ---------------------------------------------------------------------------
__global__ __launch_bounds__(512) void k_delta(const float* __restrict__ part,
    const float* __restrict__ rpn_b,
    const float* __restrict__ dw, const float* __restrict__ db,
    float* __restrict__ boxes) {
  int p = blockIdx.x;        // 0..31
  int x = p & 3, b = p >> 2;
  __shared__ float tbuf[256];
  __shared__ float dvals[135];
  int tid = threadIdx.x;
  if (tid < 256) {
    float s = rpn_b[tid];
#pragma unroll
    for (int kc = 0; kc < 16; ++kc)
      s += part[((size_t)kc * 32 + p) * 256 + tid];
    tbuf[tid] = fmaxf(s, 0.f);
  }
  __syncthreads();
  if (tid < 270) {
    int o = tid >> 1, half = tid & 1;
    const float* wp = dw + (size_t)o * 256 + half * 128;
    const float* tp = tbuf + half * 128;
    float s0 = 0.f, s1 = 0.f, s2 = 0.f, s3 = 0.f;
#pragma unroll 8
    for (int k = 0; k < 128; k += 4) {
      s0 += tp[k]     * wp[k];
      s1 += tp[k + 1] * wp[k + 1];
      s2 += tp[k + 2] * wp[k + 2];
      s3 += tp[k + 3] * wp[k + 3];
    }
    float s = (s0 + s1) + (s2 + s3);
    s += __shfl_xor(s, 1, 64);   // pair (2o, 2o+1) always within one wave
    if (half == 0) dvals[o] = s + db[o];
  }
  __syncthreads();
  if (tid < 27) {
    int i = x * 27 + tid;
    if (i < 100) {
      int a = tid;
      int si = a / 9, ri = (a / 3) % 3, ai = a % 3;
      float scale = 32.f * (float)(1 << si);
      float sr = (ri == 0) ? 0.70710678118654752f : (ri == 1 ? 1.0f : 1.41421356237309505f);
      float aw = scale * sr, ah = scale / sr;
      float aang = 45.f * (float)ai;
      float acx = 32.f * (float)x, acy = 0.f;
      float* bx = boxes + (size_t)(b * 100 + i) * 5;
      bx[0] = dvals[a * 5 + 0] * aw + acx;
      bx[1] = dvals[a * 5 + 1] * ah + acy;
      bx[2] = expf(dvals[a * 5 + 2]) * aw;
      bx[3] = expf(dvals[a * 5 + 3]) * ah;
      bx[4] = aang + dvals[a * 5 + 4];
    }
  }
}

// ---------------------------------------------------------------------------
// K3: rotated ROI align. XCD-pinned: n = (bid%8)*100 + bid/8 makes the
// image index b = bid%8 = XCD id (dispatch round-robins XCD by blockIdx),
// so each XCD's 1 MB feature slice stays resident in its own L2.
// Branch-free clamped gathers, unroll-7; pooled store 8B/lane.
// ---------------------------------------------------------------------------
__global__ __launch_bounds__(256) void k_roialign(const float* __restrict__ f,
    const float* __restrict__ boxes, bf16* __restrict__ pooled) {
  int bid = blockIdx.x;
  int n = (bid & 7) * 100 + (bid >> 3);   // bid>>3 in 0..99, bijective
  int b = bid & 7;                        // == n / 100
  __shared__ int six[49], siy[49];
  __shared__ float swx[49], swy[49];
  __shared__ float pool_s[12544];
  int tid = threadIdx.x;
  if (tid < 49) {
    float cx = boxes[n * 5 + 0], cy = boxes[n * 5 + 1];
    float w = boxes[n * 5 + 2], h = boxes[n * 5 + 3], ang = boxes[n * 5 + 4];
    float ar = -ang * 0.017453292519943295f;
    float cc = cosf(ar), ss = sinf(ar);
    float t00 = w * (1.f / 32.f) * cc, t01 = -h * (1.f / 32.f) * ss;
    float t02 = cx * (2.f / 32.f) - 1.f;
    float t10 = w * (1.f / 32.f) * ss, t11 = h * (1.f / 32.f) * cc;
    float t12 = cy * (2.f / 32.f) - 1.f;
    int py = tid / 7, px = tid - py * 7;
    float lx = (2.f * px + 1.f) * (1.f / 7.f) - 1.f;
    float ly = (2.f * py + 1.f) * (1.f / 7.f) - 1.f;
    float gx = t00 * lx + t01 * ly + t02;
    float gy = t10 * lx + t11 * ly + t12;
    float ix = ((gx + 1.f) * 32.f - 1.f) * 0.5f;
    float iy = ((gy + 1.f) * 32.f - 1.f) * 0.5f;
    float x0 = floorf(ix), y0 = floorf(iy);
    six[tid] = (int)x0; siy[tid] = (int)y0;
    swx[tid] = ix - x0; swy[tid] = iy - y0;
  }
  __syncthreads();
  const float* fb = f + (size_t)b * 262144;
  int c = tid;
#pragma unroll 7
  for (int bin = 0; bin < 49; ++bin) {
    int x0 = six[bin], y0 = siy[bin];
    float wx = swx[bin], wy = swy[bin];
    bool x0ok = (x0 >= 0) & (x0 < 32), x1ok = (x0 + 1 >= 0) & (x0 + 1 < 32);
    bool y0ok = (y0 >= 0) & (y0 < 32), y1ok = (y0 + 1 >= 0) & (y0 + 1 < 32);
    int x0c = min(max(x0, 0), 31), x1c = min(max(x0 + 1, 0), 31);
    int y0c = min(max(y0, 0), 31), y1c = min(max(y0 + 1, 0), 31);
    float w00 = (x0ok && y0ok) ? (1.f - wx) * (1.f - wy) : 0.f;
    float w01 = (x1ok && y0ok) ? wx * (1.f - wy) : 0.f;
    float w10 = (x0ok && y1ok) ? (1.f - wx) * wy : 0.f;
    float w11 = (x1ok && y1ok) ? wx * wy : 0.f;
    float acc = fb[(y0c * 32 + x0c) * 256 + c] * w00
              + fb[(y0c * 32 + x1c) * 256 + c] * w01
              + fb[(y1c * 32 + x0c) * 256 + c] * w10
              + fb[(y1c * 32 + x1c) * 256 + c] * w11;
    pool_s[c * 49 + bin] = acc;
  }
  __syncthreads();
  uint2* po = (uint2*)(pooled + (size_t)n * 12544);   // 3136 x 8B
  for (int k = tid; k < 3136; k += 256) {
    f32x4 v = *(const f32x4*)&pool_s[k * 4];
    uint2 o; o.x = pk2(v[0], v[1]); o.y = pk2(v[2], v[3]);
    po[k] = o;
  }
}

// ---------------------------------------------------------------------------
// K-cvt1: fc1_w fp32 -> bf16 (runs after roialign; bw1 aliases f).
// ---------------------------------------------------------------------------
__global__ __launch_bounds__(256) void k_cvt1(const float* __restrict__ s1,
    uint2* __restrict__ d1) {
  const int N1 = 3211264;   // fc1_w float4s (1024*12544/4)
  int stride = gridDim.x * 256;
  for (int j = blockIdx.x * 256 + threadIdx.x; j < N1; j += stride) {
    float4 v = ((const float4*)s1)[j];
    uint2 o; o.x = pk2(v.x, v.y); o.y = pk2(v.z, v.w);
    d1[j] = o;
  }
}

// ---------------------------------------------------------------------------
// K4: both-bf16 split-K MFMA GEMM, counted-vmcnt double-buffer (T3+T4) +
// XCD-pinned split-K (T1): all 56 tile-blocks of K-chunk z land on XCD z%8.
// Per-z working set ~3.3 MB fits one XCD's 4 MB L2 (R7: FETCH 92->25 MB).
// Tile 128x128, BK=64, 4 waves (2x2), 32 MFMA/wave/step, atomic accum.
// Block decode: xcd=b&7, g=(b>>3)/56, t2=(b>>3)%56, z=xcd+8g.
// ---------------------------------------------------------------------------
__global__ __launch_bounds__(256) void k_gemm_bb(
    const unsigned short* __restrict__ A, const unsigned short* __restrict__ B,
    float* __restrict__ P, int M, int N, int K, int KC) {
  int b = blockIdx.x;
  int xcd = b & 7, j = b >> 3;
  int g = j / 56, t2 = j - g * 56;
  int z = xcd + 8 * g;
  int kbeg = z * KC;
  if (kbeg >= K) return;                   // idle padding block
  int kend = kbeg + KC; if (kend > K) kend = K;
  int n0 = (t2 & 7) * 128;                 // n-tile (N=1024 -> 8 tiles)
  int m0 = (t2 >> 3) * 128;                // m-tile (M=800  -> 7 tiles)

  __shared__ unsigned short As[2][128 * 64];  // 2 x 16 KB
  __shared__ unsigned short Bs[2][128 * 64];  // 2 x 16 KB
  int t = threadIdx.x;
  int wv = t >> 6, ln = t & 63;
  int quad = ln >> 4, l15 = ln & 15;
  int wm = wv >> 1, wn = wv & 1;           // 2x2 wave grid

  // Staging: lane (srow, sg): within-8-row-group row srow, global seg
  // sg = (ln&7)^srow lands at linear LDS slot (ln&7) -> XOR swizzle.
  int srow = ln >> 3;                      // 0..7
  int sg = (ln & 7) ^ srow;
  const unsigned short* Ap[4];
#pragma unroll
  for (int q = 0; q < 4; ++q) {
    int r = m0 + q * 32 + wv * 8 + srow;   // within-tile row & 7 == srow
    if (r > M - 1) r = M - 1;
    Ap[q] = A + (size_t)r * K + sg * 8;
  }
  const unsigned short* Bp[4];
#pragma unroll
  for (int c = 0; c < 4; ++c) {
    int r = n0 + wv * 32 + c * 8 + srow;   // N=1024: always in range
    Bp[c] = B + (size_t)r * K + sg * 8;
  }

  f32x4 acc[4][4];
#pragma unroll
  for (int mf = 0; mf < 4; ++mf)
#pragma unroll
    for (int nf = 0; nf < 4; ++nf) acc[mf][nf] = (f32x4){0.f, 0.f, 0.f, 0.f};

  // prologue: stage tile kbeg into buffer 0 (8 async16/wave, in flight)
#pragma unroll
  for (int q = 0; q < 4; ++q)
    async16(Ap[q] + kbeg, &As[0][q * 2048 + wv * 512]);
#pragma unroll
  for (int c = 0; c < 4; ++c)
    async16(Bp[c] + kbeg, &Bs[0][wv * 2048 + c * 512]);

  int cur = 0;
  for (int k0 = kbeg; k0 < kend; k0 += 64) {
    int k1 = k0 + 64;
    if (k1 < kend) {
      // stage next tile into buf^1 (that buffer's readers finished at the
      // barrier that ended the previous iteration -> WAR-safe).
#pragma unroll
      for (int q = 0; q < 4; ++q)
        async16(Ap[q] + k1, &As[cur ^ 1][q * 2048 + wv * 512]);
#pragma unroll
      for (int c = 0; c < 4; ++c)
        async16(Bp[c] + k1, &Bs[cur ^ 1][wv * 2048 + c * 512]);
      // wait for the OLD 8 only; the new 8 stay in flight across the barrier
      asm volatile("s_waitcnt vmcnt(8)" ::: "memory");
    } else {
      asm volatile("s_waitcnt vmcnt(0)" ::: "memory");
    }
    __builtin_amdgcn_s_barrier();          // all waves: buf[cur] resident
    __builtin_amdgcn_sched_barrier(0);
#pragma unroll
    for (int ks = 0; ks < 2; ++ks) {
      bf16x8 a[4];
#pragma unroll
      for (int mf = 0; mf < 4; ++mf) {
        int row = wm * 64 + mf * 16 + l15;           // row & 7 == l15 & 7
        a[mf] = *(const bf16x8*)&As[cur][row * 64 + (((ks * 4 + quad) ^ (l15 & 7)) * 8)];
      }
#pragma unroll
      for (int nf = 0; nf < 4; ++nf) {
        int brow = wn * 64 + nf * 16 + l15;
        bf16x8 b2 = *(const bf16x8*)&Bs[cur][brow * 64 + (((ks * 4 + quad) ^ (l15 & 7)) * 8)];
#pragma unroll
        for (int mf = 0; mf < 4; ++mf)
          acc[mf][nf] = __builtin_amdgcn_mfma_f32_16x16x32_bf16(a[mf], b2, acc[mf][nf], 0, 0, 0);
      }
    }
    __builtin_amdgcn_sched_barrier(0);
    asm volatile("" ::: "memory");
    __builtin_amdgcn_s_barrier();          // readers of buf[cur] done ->
    cur ^= 1;                              // next iter may restage into it
  }
  // atomic accumulate; D layout m = quad*4+r, n = l15 (within 16x16).
#pragma unroll
  for (int nf = 0; nf < 4; ++nf) {
    int n = n0 + wn * 64 + nf * 16 + l15;
#pragma unroll
    for (int mf = 0; mf < 4; ++mf) {
#pragma unroll
      for (int r = 0; r < 4; ++r) {
        int m = m0 + wm * 64 + mf * 16 + quad * 4 + r;
        if (m < M) atomicAdd(&P[(size_t)m * N + n], acc[mf][nf][r]);
      }
    }
  }
}

// ---------------------------------------------------------------------------
// K5: bias + ReLU epilogue: C = relu(P + bias); re-zeros P for the next
// atomic GEMM. float4-vectorized.
// ---------------------------------------------------------------------------
template <typename OutT, bool RZ>
__global__ __launch_bounds__(256) void k_bias_relu(float* __restrict__ P,
    const float* __restrict__ bias, OutT* __restrict__ C, int MN, int N) {
  int i = blockIdx.x * 256 + threadIdx.x;   // float4 index
  if (i * 4 >= MN) return;
  f32x4 s = *(const f32x4*)(P + (size_t)i * 4);
  int n = (i * 4) % N;
#pragma unroll
  for (int u = 0; u < 4; ++u)
    store_o(C, (size_t)i * 4 + u, fmaxf(s[u] + bias[n + u], 0.f));
  if (RZ) *(f32x4*)(P + (size_t)i * 4) = (f32x4){0.f, 0.f, 0.f, 0.f};
}

// ---------------------------------------------------------------------------
// K6: heads FUSED with FC2 epilogue: x2row = relu(P[n] + fc2_b) built in
// LDS, then one wave per output (5 cls + 5 bbox).
// ---------------------------------------------------------------------------
__global__ __launch_bounds__(640) void k_heads(const float* __restrict__ P,
    const float* __restrict__ fc2_b,
    const float* __restrict__ cls_w, const float* __restrict__ cls_b,
    const float* __restrict__ bbox_w, const float* __restrict__ bbox_b,
    float* __restrict__ out) {
  __shared__ float xr[1024];
  int n = blockIdx.x;
  for (int i = threadIdx.x; i < 1024; i += 640)
    xr[i] = fmaxf(P[(size_t)n * 1024 + i] + fc2_b[i], 0.f);
  __syncthreads();
  int wave = threadIdx.x >> 6;   // 0..9
  int lane = threadIdx.x & 63;
  const float* w = (wave < 5) ? (cls_w + (size_t)wave * 1024)
                              : (bbox_w + (size_t)(wave - 5) * 1024);
  float s = 0.f;
  for (int k = lane; k < 1024; k += 64) s += xr[k] * w[k];
  for (int off = 32; off; off >>= 1) s += __shfl_down(s, off, 64);
  if (lane == 0) {
    int o = (wave < 5) ? wave : wave - 5;
    float bias = (wave < 5) ? cls_b[o] : bbox_b[o];
    int base = (wave < 5) ? 0 : 4000;
    out[base + n * 5 + o] = s + bias;
  }
}

// ---------------------------------------------------------------------------
extern "C" void kernel_launch(void* const* d_in, const int* in_sizes, int n_in,
                              void* d_out, int out_size, void* d_ws, size_t ws_size,
                              hipStream_t stream) {
  const float* images     = (const float*)d_in[0];
  const float* backbone_w = (const float*)d_in[1];
  const float* backbone_b = (const float*)d_in[2];
  const float* rpn_w      = (const float*)d_in[3];
  const float* rpn_b      = (const float*)d_in[4];
  // d_in[5]/d_in[6] (obj_w/obj_b): conv output unused by the reference.
  const float* delta_w    = (const float*)d_in[7];
  const float* delta_b    = (const float*)d_in[8];
  const float* fc1_w      = (const float*)d_in[9];
  const float* fc1_b      = (const float*)d_in[10];
  const float* fc2_w      = (const float*)d_in[11];
  const float* fc2_b      = (const float*)d_in[12];
  const float* cls_w      = (const float*)d_in[13];
  const float* cls_b      = (const float*)d_in[14];
  const float* bbox_w     = (const float*)d_in[15];
  const float* bbox_b     = (const float*)d_in[16];

  // Workspace layout (52.79 MB; aliases stream-ordered):
  //   bw1 @ 0          : 25,690,112 B (fc1_w bf16)  -- ALIASES f (8.39 MB,
  //                      dead after k_roialign; k_cvt1 runs after it)
  //   boxes @25,690,112:     16,384 B
  //   pooled@25,706,496: 20,070,400 B -- its first 512 KB also hosts the
  //                      rpn partials (consumed by k_delta BEFORE roialign
  //                      overwrites; stream-ordered)
  //   x1   @45,776,896 :  1,638,400 B
  //   P    @47,415,296 :  3,276,800 B (atomic accum; zeroed in k_backbone
  //                      aux blocks; heads reads FC2 result from here)
  //   bw2  @50,692,096 :  2,097,152 B (fc2_w bf16; written by backbone aux)
  char* ws = (char*)d_ws;
  bf16*  bw1    = (bf16*) ws;
  float* f      = (float*)ws;                  // phase-1 only
  float* boxes  = (float*)(ws + 25690112);
  bf16*  pooled = (bf16*) (ws + 25706496);
  float* rpart  = (float*)(ws + 25706496);     // alias: pre-roialign scratch
  bf16*  x1     = (bf16*) (ws + 45776896);
  float* P      = (float*)(ws + 47415296);
  bf16*  bw2    = (bf16*) (ws + 50692096);

  // backbone + fused aux (fc2_w cvt + zero P): 2048 + 256 blocks
  k_backbone<<<2304, 256, 0, stream>>>(images, backbone_w, backbone_b, f,
                                       fc2_w, (uint2*)bw2, (f32x4*)P);
  k_rpn<<<dim3(32, 16), 256, 0, stream>>>(f, rpn_w, rpart);
  k_delta<<<32, 512, 0, stream>>>(rpart, rpn_b, delta_w, delta_b, boxes);
  k_roialign<<<800, 256, 0, stream>>>(f, boxes, pooled);

  // fc1_w pre-conversion (f dead; bw1 overwrites its region)
  k_cvt1<<<2048, 256, 0, stream>>>(fc1_w, (uint2*)bw1);

  // FC1: K=12544, KS=14 (KC=896). XCD-pinned grid: 896 blocks
  // (784 working + 112 idle pads so that XCD(b)=b%8 == z%8).
  k_gemm_bb<<<896, 256, 0, stream>>>(
      (const unsigned short*)pooled, (const unsigned short*)bw1, P,
      800, 1024, 12544, 896);
  k_bias_relu<bf16, true><<<800, 256, 0, stream>>>(P, fc1_b, x1, 819200, 1024);

  // FC2: K=1024, KS=8 (KC=128), one z per XCD. 448 blocks.
  k_gemm_bb<<<448, 256, 0, stream>>>(
      (const unsigned short*)x1, (const unsigned short*)bw2, P,
      800, 1024, 1024, 128);

  // heads fused with FC2 bias+relu (reads P directly)
  k_heads<<<800, 640, 0, stream>>>(P, fc2_b, cls_w, cls_b, bbox_w, bbox_b,
                                   (float*)d_out);
}